// Round 5
// baseline (467.621 us; speedup 1.0000x reference)
//
#include <hip/hip_runtime.h>
#include <hip/hip_bf16.h>
#include <math.h>

#define NUM_USERS  100000
#define NUM_ITEMS  50000
#define N_NODES    150000
#define EMBED_DIM  64
#define NUM_EDGES  1250000
#define MLP_HID    32
#define SCAN_B     1024
#define SCAN_NB    ((N_NODES + SCAN_B - 1) / SCAN_B)   // 147
#define NPW        4                                   // nodes per wave
#define PAD(x)     (((x) + 15) & ~15)                  // segment pad to 16

// ---------------------------------------------------------------------------
// hist + deg + per-edge MLP fused: rank via int atomicAdd (rank IS the CSR
// slot), deg via float atomicAdd (raw w), epair[e]={src,w} streaming.
// ---------------------------------------------------------------------------
__global__ void hist_mlp(const float* __restrict__ edge_attr,
                         const float* __restrict__ ew,
                         const float* __restrict__ w1,
                         const float* __restrict__ b1,
                         const float* __restrict__ w2,
                         const float* __restrict__ b2,
                         const int*   __restrict__ edge_index,
                         int*   __restrict__ cnt,
                         float* __restrict__ deg,
                         int*   __restrict__ rank,
                         int2*  __restrict__ epair) {
    __shared__ float w1s[8 * MLP_HID];
    __shared__ float b1s[MLP_HID];
    __shared__ float w2s[MLP_HID];
    int tid = threadIdx.x;
    if (tid < 8 * MLP_HID) w1s[tid] = w1[tid];
    if (tid < MLP_HID) { b1s[tid] = b1[tid]; w2s[tid] = w2[tid]; }
    __syncthreads();

    int e = blockIdx.x * blockDim.x + tid;
    if (e >= NUM_EDGES) return;

    int c = edge_index[NUM_EDGES + e];
    rank[e] = atomicAdd(&cnt[c], 1);

    float ef[8];
#pragma unroll
    for (int k = 0; k < 7; ++k) ef[k] = edge_attr[e * 7 + k];
    ef[7] = ew[e];

    float s = b2[0];
#pragma unroll
    for (int j = 0; j < MLP_HID; ++j) {
        float h = b1s[j];
#pragma unroll
        for (int k = 0; k < 8; ++k) h = fmaf(ef[k], w1s[k * MLP_HID + j], h);
        h = fmaxf(h, 0.0f);
        s = fmaf(h, w2s[j], s);
    }
    float w = 1.0f / (1.0f + expf(-s));

    atomicAdd(&deg[c], w);

    int2 pr;
    pr.x = edge_index[e];          // src row
    pr.y = __float_as_int(w);
    epair[e] = pr;                 // streaming, coalesced
}

// ---------------------------------------------------------------------------
// Device-wide exclusive scan of PAD16(cnt) -> row_ptr, 3 phases.
// ---------------------------------------------------------------------------
__global__ void scan_partial(const int* __restrict__ cnt,
                             int* __restrict__ part) {
    __shared__ int s[SCAN_B];
    int tid = threadIdx.x;
    int i = blockIdx.x * SCAN_B + tid;
    s[tid] = (i < N_NODES) ? PAD(cnt[i]) : 0;
    __syncthreads();
#pragma unroll
    for (int off = SCAN_B / 2; off > 0; off >>= 1) {
        if (tid < off) s[tid] += s[tid + off];
        __syncthreads();
    }
    if (tid == 0) part[blockIdx.x] = s[0];
}

__global__ void scan_offsets(const int* __restrict__ part,
                             int* __restrict__ base_off) {
    __shared__ int s[256];
    int tid = threadIdx.x;
    int v = (tid < SCAN_NB) ? part[tid] : 0;
    s[tid] = v;
    __syncthreads();
#pragma unroll
    for (int off = 1; off < 256; off <<= 1) {
        int t = (tid >= off) ? s[tid - off] : 0;
        __syncthreads();
        s[tid] += t;
        __syncthreads();
    }
    if (tid < SCAN_NB) base_off[tid] = s[tid] - v;   // exclusive
}

__global__ void scan_apply(const int* __restrict__ cnt,
                           const int* __restrict__ base_off,
                           int* __restrict__ row_ptr) {
    __shared__ int s[SCAN_B];
    int tid = threadIdx.x;
    int i = blockIdx.x * SCAN_B + tid;
    int v = (i < N_NODES) ? PAD(cnt[i]) : 0;
    s[tid] = v;
    __syncthreads();
    for (int off = 1; off < SCAN_B; off <<= 1) {
        int t = (tid >= off) ? s[tid - off] : 0;
        __syncthreads();
        s[tid] += t;
        __syncthreads();
    }
    if (i < N_NODES) row_ptr[i] = s[tid] - v + base_off[blockIdx.x];
    if (i == N_NODES - 1) row_ptr[N_NODES] = s[tid] + base_off[blockIdx.x];
}

// ---------------------------------------------------------------------------
// dinv[n] = rsqrt(deg) ; also zero 64-pair tail after padded CSR end so the
// propagate pipeline's overrun reads are {src=0, w=0}.
// ---------------------------------------------------------------------------
__global__ void make_dinv(const float* __restrict__ deg,
                          float* __restrict__ dinv,
                          const int* __restrict__ row_ptr,
                          int2* __restrict__ csr_pair) {
    int t = blockIdx.x * blockDim.x + threadIdx.x;
    if (t < N_NODES) {
        float d = deg[t];
        dinv[t] = (d > 0.0f) ? rsqrtf(fmaxf(d, 1e-30f)) : 0.0f;
    }
    if (t < 64) {
        int end = row_ptr[N_NODES];
        int2 z; z.x = 0; z.y = 0;
        csr_pair[end + t] = z;
    }
}

// ---------------------------------------------------------------------------
// perm[row_ptr[c] + rank[e]] = e    (4B random scatter — the only one left)
// ---------------------------------------------------------------------------
__global__ void scatter_perm(const int* __restrict__ edge_index,
                             const int* __restrict__ rank,
                             const int* __restrict__ row_ptr,
                             int* __restrict__ perm) {
    int e = blockIdx.x * blockDim.x + threadIdx.x;
    if (e >= NUM_EDGES) return;
    int c = edge_index[NUM_EDGES + e];
    perm[row_ptr[c] + rank[e]] = e;
}

// ---------------------------------------------------------------------------
// Build padded CSR in GATHER mode with FULLY-SCALED weights:
// pair.w = w * dinv[src] * dinv[col].  Pads zeroed inline.
// ---------------------------------------------------------------------------
__global__ void pair_build(const int* __restrict__ row_ptr,
                           const int* __restrict__ cnt,
                           const int* __restrict__ perm,
                           const int2* __restrict__ epair,
                           const float* __restrict__ dinv,
                           int2* __restrict__ csr_pair) {
    int t = blockIdx.x * blockDim.x + threadIdx.x;
    int node = t >> 4;
    int lane = t & 15;
    if (node >= N_NODES) return;
    int s = row_ptr[node];
    int e = row_ptr[node + 1];
    int re = s + cnt[node];
    float dc = dinv[node];
    for (int j = s + lane; j < e; j += 16) {
        int2 pr;
        if (j < re) {
            int eid = perm[j];
            pr = epair[eid];
            pr.y = __float_as_int(__int_as_float(pr.y) * dc * dinv[pr.x]);
        } else {
            pr.x = 0; pr.y = 0;
        }
        csr_pair[j] = pr;
    }
}

// ---------------------------------------------------------------------------
// build x0: bf16 only.
// ---------------------------------------------------------------------------
__global__ void init_x(const float* __restrict__ user_w,
                       const float* __restrict__ artist_w,
                       const float* __restrict__ album_w,
                       const float* __restrict__ audio,
                       const int*   __restrict__ artist_ids,
                       const int*   __restrict__ album_ids,
                       __hip_bfloat16* __restrict__ x) {
    int t = blockIdx.x * blockDim.x + threadIdx.x;
    int row = t >> 6;
    int lane = t & 63;
    if (row >= N_NODES) return;

    float v;
    if (row < NUM_USERS) {
        v = user_w[row * EMBED_DIM + lane];
    } else {
        int r = row - NUM_USERS;
        int ar = artist_ids[r];
        int al = album_ids[r];
        v = audio[r * EMBED_DIM + lane]
          + 0.5f * (artist_w[ar * EMBED_DIM + lane] + album_w[al * EMBED_DIM + lane]);
    }
    float ss = v * v;
#pragma unroll
    for (int off = 32; off > 0; off >>= 1) ss += __shfl_xor(ss, off);
    float scale = 1.0f / fmaxf(sqrtf(ss), 1e-12f);
    x[row * EMBED_DIM + lane] = __float2bfloat16(v * scale);
}

// ---------------------------------------------------------------------------
// pull-mode propagation v6: NPW(4) nodes/wave, pad-16 CSR, SOFTWARE-PIPELINED
// flat group stream:
//   iteration i: issue gathers for group i+1 (UB from PB), load pairs for
//   group i+2 (PC), FMA group i (UA, issued one FULL iteration ago).
// Node boundaries coincide with group boundaries (pad-16); finalization is a
// wave-uniform branch (rs values identical across lanes).  Weights are fully
// pre-scaled -> zero per-edge dinv loads.  Last-group overrun gathers are
// guarded to row 0; pair overrun reads land in the zeroed 64-pair tail.
// ---------------------------------------------------------------------------
#define BF_LO(u) __uint_as_float((u) << 16)
#define BF_HI(u) __uint_as_float((u) & 0xffff0000u)

#define REDUCE_ACC()                                                         \
    a0 += __shfl_xor(a0, 16); a1 += __shfl_xor(a1, 16);                      \
    a2 += __shfl_xor(a2, 16); a3 += __shfl_xor(a3, 16);                      \
    a0 += __shfl_xor(a0, 32); a1 += __shfl_xor(a1, 32);                      \
    a2 += __shfl_xor(a2, 32); a3 += __shfl_xor(a3, 32)

#define NEXT_BOUND() ((k == 1) ? rs2 : (k == 2) ? rs3 : rs4)

__global__ void propagate_mid(const int* __restrict__ row_ptr,
                              const int2* __restrict__ csr_pair,
                              const unsigned short* __restrict__ xin,
                              unsigned short* __restrict__ xout) {
    int wave = (blockIdx.x * blockDim.x + threadIdx.x) >> 6;
    int lane = threadIdx.x & 63;
    int node0 = wave * NPW;
    if (node0 >= N_NODES) return;

    int eg = lane >> 4;          // edge slot group 0..3 (4 edges each)
    int dq = (lane & 15) << 2;   // dim quad start

    int rpv = row_ptr[node0 + (lane <= NPW ? lane : NPW)];
    int rs0 = __shfl(rpv, 0);
    int rs1 = __shfl(rpv, 1);
    int rs2 = __shfl(rpv, 2);
    int rs3 = __shfl(rpv, 3);
    int rs4 = __shfl(rpv, 4);

    float a0 = 0, a1 = 0, a2 = 0, a3 = 0;
    int k = 0;
    int bnext = rs1;

#define STORE_MID()                                                          \
    do {                                                                     \
        if (eg == 0) {                                                       \
            size_t o = ((size_t)(node0 + k) << 6) + dq;                      \
            unsigned int b0 = (unsigned int)__bfloat16_as_ushort(__float2bfloat16(a0)); \
            unsigned int b1 = (unsigned int)__bfloat16_as_ushort(__float2bfloat16(a1)); \
            unsigned int b2 = (unsigned int)__bfloat16_as_ushort(__float2bfloat16(a2)); \
            unsigned int b3 = (unsigned int)__bfloat16_as_ushort(__float2bfloat16(a3)); \
            uint2 u;                                                         \
            u.x = b0 | (b1 << 16);                                           \
            u.y = b2 | (b3 << 16);                                           \
            *(uint2*)(xout + o) = u;                                         \
        }                                                                    \
    } while (0)

    // leading empty nodes
    while (k < NPW && rs0 == bnext) {
        STORE_MID();               // acc is zero
        ++k;
        bnext = NEXT_BOUND();
    }

    // pipeline prologue
    int j = rs0 + (eg << 2);
    int2 pa0 = csr_pair[j],      pa1 = csr_pair[j + 1];
    int2 pa2 = csr_pair[j + 2],  pa3 = csr_pair[j + 3];
    uint2 ua0 = *(const uint2*)(xin + ((size_t)pa0.x << 6) + dq);
    uint2 ua1 = *(const uint2*)(xin + ((size_t)pa1.x << 6) + dq);
    uint2 ua2 = *(const uint2*)(xin + ((size_t)pa2.x << 6) + dq);
    uint2 ua3 = *(const uint2*)(xin + ((size_t)pa3.x << 6) + dq);
    int2 pb0 = csr_pair[j + 16], pb1 = csr_pair[j + 17];
    int2 pb2 = csr_pair[j + 18], pb3 = csr_pair[j + 19];

    for (int base = rs0; base < rs4; base += 16) {
        // issue next group's gathers (guard overrun to row 0)
        bool live = (base + 16) < rs4;
        int sb0 = live ? pb0.x : 0;
        int sb1 = live ? pb1.x : 0;
        int sb2 = live ? pb2.x : 0;
        int sb3 = live ? pb3.x : 0;
        uint2 ub0 = *(const uint2*)(xin + ((size_t)sb0 << 6) + dq);
        uint2 ub1 = *(const uint2*)(xin + ((size_t)sb1 << 6) + dq);
        uint2 ub2 = *(const uint2*)(xin + ((size_t)sb2 << 6) + dq);
        uint2 ub3 = *(const uint2*)(xin + ((size_t)sb3 << 6) + dq);
        // load pairs two groups ahead
        int2 pc0 = csr_pair[j + 32], pc1 = csr_pair[j + 33];
        int2 pc2 = csr_pair[j + 34], pc3 = csr_pair[j + 35];

        // FMA current group (gathers issued one full iteration ago)
        float w0 = __int_as_float(pa0.y);
        float w1 = __int_as_float(pa1.y);
        float w2 = __int_as_float(pa2.y);
        float w3 = __int_as_float(pa3.y);
        a0 = fmaf(w0, BF_LO(ua0.x), a0); a1 = fmaf(w0, BF_HI(ua0.x), a1);
        a2 = fmaf(w0, BF_LO(ua0.y), a2); a3 = fmaf(w0, BF_HI(ua0.y), a3);
        a0 = fmaf(w1, BF_LO(ua1.x), a0); a1 = fmaf(w1, BF_HI(ua1.x), a1);
        a2 = fmaf(w1, BF_LO(ua1.y), a2); a3 = fmaf(w1, BF_HI(ua1.y), a3);
        a0 = fmaf(w2, BF_LO(ua2.x), a0); a1 = fmaf(w2, BF_HI(ua2.x), a1);
        a2 = fmaf(w2, BF_LO(ua2.y), a2); a3 = fmaf(w2, BF_HI(ua2.y), a3);
        a0 = fmaf(w3, BF_LO(ua3.x), a0); a1 = fmaf(w3, BF_HI(ua3.x), a1);
        a2 = fmaf(w3, BF_LO(ua3.y), a2); a3 = fmaf(w3, BF_HI(ua3.y), a3);

        // rotate pipeline registers
        pa0 = pb0; pa1 = pb1; pa2 = pb2; pa3 = pb3;
        pb0 = pc0; pb1 = pc1; pb2 = pc2; pb3 = pc3;
        ua0 = ub0; ua1 = ub1; ua2 = ub2; ua3 = ub3;
        j += 16;

        // node boundary (wave-uniform)
        int pos = base + 16;
        while (k < NPW && pos == bnext) {
            REDUCE_ACC();
            STORE_MID();
            a0 = 0; a1 = 0; a2 = 0; a3 = 0;
            ++k;
            bnext = NEXT_BOUND();
        }
    }
#undef STORE_MID
}

// ---------------------------------------------------------------------------
// FINAL layer: gather from x2, then out = l2norm((x0+x1+x2+a)/4), f32.
// ---------------------------------------------------------------------------
__global__ void propagate_final(const int* __restrict__ row_ptr,
                                const int2* __restrict__ csr_pair,
                                const unsigned short* __restrict__ x0,
                                const unsigned short* __restrict__ x1,
                                const unsigned short* __restrict__ x2,
                                float* __restrict__ outp) {
    int wave = (blockIdx.x * blockDim.x + threadIdx.x) >> 6;
    int lane = threadIdx.x & 63;
    int node0 = wave * NPW;
    if (node0 >= N_NODES) return;

    int eg = lane >> 4;
    int dq = (lane & 15) << 2;

    int rpv = row_ptr[node0 + (lane <= NPW ? lane : NPW)];
    int rs0 = __shfl(rpv, 0);
    int rs1 = __shfl(rpv, 1);
    int rs2 = __shfl(rpv, 2);
    int rs3 = __shfl(rpv, 3);
    int rs4 = __shfl(rpv, 4);

    float a0 = 0, a1 = 0, a2 = 0, a3 = 0;
    int k = 0;
    int bnext = rs1;

#define STORE_FIN()                                                          \
    do {                                                                     \
        if (eg == 0) {                                                       \
            size_t o = ((size_t)(node0 + k) << 6) + dq;                      \
            uint2 u0 = *(const uint2*)(x0 + o);                              \
            uint2 u1 = *(const uint2*)(x1 + o);                              \
            uint2 u2 = *(const uint2*)(x2 + o);                              \
            float v0 = (BF_LO(u0.x) + BF_LO(u1.x) + BF_LO(u2.x) + a0) * 0.25f; \
            float v1 = (BF_HI(u0.x) + BF_HI(u1.x) + BF_HI(u2.x) + a1) * 0.25f; \
            float v2 = (BF_LO(u0.y) + BF_LO(u1.y) + BF_LO(u2.y) + a2) * 0.25f; \
            float v3 = (BF_HI(u0.y) + BF_HI(u1.y) + BF_HI(u2.y) + a3) * 0.25f; \
            float ss = v0 * v0 + v1 * v1 + v2 * v2 + v3 * v3;                \
            ss += __shfl_xor(ss, 1);                                         \
            ss += __shfl_xor(ss, 2);                                         \
            ss += __shfl_xor(ss, 4);                                         \
            ss += __shfl_xor(ss, 8);                                         \
            float scale = 1.0f / fmaxf(sqrtf(ss), 1e-12f);                   \
            float4 r = { v0 * scale, v1 * scale, v2 * scale, v3 * scale };   \
            *(float4*)(outp + o) = r;                                        \
        }                                                                    \
    } while (0)

    while (k < NPW && rs0 == bnext) {
        STORE_FIN();
        ++k;
        bnext = NEXT_BOUND();
    }

    int j = rs0 + (eg << 2);
    int2 pa0 = csr_pair[j],      pa1 = csr_pair[j + 1];
    int2 pa2 = csr_pair[j + 2],  pa3 = csr_pair[j + 3];
    uint2 ua0 = *(const uint2*)(x2 + ((size_t)pa0.x << 6) + dq);
    uint2 ua1 = *(const uint2*)(x2 + ((size_t)pa1.x << 6) + dq);
    uint2 ua2 = *(const uint2*)(x2 + ((size_t)pa2.x << 6) + dq);
    uint2 ua3 = *(const uint2*)(x2 + ((size_t)pa3.x << 6) + dq);
    int2 pb0 = csr_pair[j + 16], pb1 = csr_pair[j + 17];
    int2 pb2 = csr_pair[j + 18], pb3 = csr_pair[j + 19];

    for (int base = rs0; base < rs4; base += 16) {
        bool live = (base + 16) < rs4;
        int sb0 = live ? pb0.x : 0;
        int sb1 = live ? pb1.x : 0;
        int sb2 = live ? pb2.x : 0;
        int sb3 = live ? pb3.x : 0;
        uint2 ub0 = *(const uint2*)(x2 + ((size_t)sb0 << 6) + dq);
        uint2 ub1 = *(const uint2*)(x2 + ((size_t)sb1 << 6) + dq);
        uint2 ub2 = *(const uint2*)(x2 + ((size_t)sb2 << 6) + dq);
        uint2 ub3 = *(const uint2*)(x2 + ((size_t)sb3 << 6) + dq);
        int2 pc0 = csr_pair[j + 32], pc1 = csr_pair[j + 33];
        int2 pc2 = csr_pair[j + 34], pc3 = csr_pair[j + 35];

        float w0 = __int_as_float(pa0.y);
        float w1 = __int_as_float(pa1.y);
        float w2 = __int_as_float(pa2.y);
        float w3 = __int_as_float(pa3.y);
        a0 = fmaf(w0, BF_LO(ua0.x), a0); a1 = fmaf(w0, BF_HI(ua0.x), a1);
        a2 = fmaf(w0, BF_LO(ua0.y), a2); a3 = fmaf(w0, BF_HI(ua0.y), a3);
        a0 = fmaf(w1, BF_LO(ua1.x), a0); a1 = fmaf(w1, BF_HI(ua1.x), a1);
        a2 = fmaf(w1, BF_LO(ua1.y), a2); a3 = fmaf(w1, BF_HI(ua1.y), a3);
        a0 = fmaf(w2, BF_LO(ua2.x), a0); a1 = fmaf(w2, BF_HI(ua2.x), a1);
        a2 = fmaf(w2, BF_LO(ua2.y), a2); a3 = fmaf(w2, BF_HI(ua2.y), a3);
        a0 = fmaf(w3, BF_LO(ua3.x), a0); a1 = fmaf(w3, BF_HI(ua3.x), a1);
        a2 = fmaf(w3, BF_LO(ua3.y), a2); a3 = fmaf(w3, BF_HI(ua3.y), a3);

        pa0 = pb0; pa1 = pb1; pa2 = pb2; pa3 = pb3;
        pb0 = pc0; pb1 = pc1; pb2 = pc2; pb3 = pc3;
        ua0 = ub0; ua1 = ub1; ua2 = ub2; ua3 = ub3;
        j += 16;

        int pos = base + 16;
        while (k < NPW && pos == bnext) {
            REDUCE_ACC();
            STORE_FIN();
            a0 = 0; a1 = 0; a2 = 0; a3 = 0;
            ++k;
            bnext = NEXT_BOUND();
        }
    }
#undef STORE_FIN
    if (blockIdx.x == 0 && threadIdx.x == 0)
        outp[(size_t)N_NODES * EMBED_DIM] = 0.0f;  // align_loss
}

#undef BF_LO
#undef BF_HI

// ---------------------------------------------------------------------------
extern "C" void kernel_launch(void* const* d_in, const int* in_sizes, int n_in,
                              void* d_out, int out_size, void* d_ws, size_t ws_size,
                              hipStream_t stream) {
    const float* user_w     = (const float*)d_in[0];
    const float* artist_w   = (const float*)d_in[1];
    const float* album_w    = (const float*)d_in[2];
    const float* audio      = (const float*)d_in[3];
    const float* edge_attr  = (const float*)d_in[4];
    const float* ew         = (const float*)d_in[5];
    const float* w1         = (const float*)d_in[6];
    const float* b1         = (const float*)d_in[7];
    const float* w2         = (const float*)d_in[8];
    const float* b2         = (const float*)d_in[9];
    const int*   edge_index = (const int*)d_in[10];
    const int*   artist_ids = (const int*)d_in[11];
    const int*   album_ids  = (const int*)d_in[12];
    float* out = (float*)d_out;

    float* ws = (float*)d_ws;
    // Persistent regions (float-unit offsets):
    unsigned short* x0 = (unsigned short*)ws;                // 9.6M bf16 (0..4.8M)
    unsigned short* x1 = (unsigned short*)(ws + 4800000);    // 9.6M bf16
    unsigned short* x2 = (unsigned short*)(ws + 9600000);    // 9.6M bf16
    float* dinv    = ws + 14400000;                          // 150k floats
    int*  row_ptr  = (int*)(ws + 14560000);                  // 150001 ints
    int2* csr_pair = (int2*)(ws + 14720000);                 // padded-16 CSR
                                                             // (<=3.5M pairs
                                                             // + 64 tail)
    // Transients aliased into x0/x1 region (dead before init_x / propagate):
    int*   cnt     = (int*)ws;                               // 150k ints
    float* deg     = ws + 150000;                            // 150k floats
    int*   rank    = (int*)(ws + 300000);                    // 1.25M ints
    int*   part    = (int*)(ws + 1600000);                   // 147 ints
    int*   baseoff = (int*)(ws + 1601000);                   // 147 ints
    int2*  epair   = (int2*)(ws + 1700000);                  // 1.25M pairs
    int*   perm    = (int*)(ws + 4800000);                   // <=3.5M ints (x1)

    const int B = 256;
    const int egrid   = (NUM_EDGES + B - 1) / B;
    const int ngrid   = (N_NODES * EMBED_DIM) / B;           // wave-per-node
    const int ngrid16 = (N_NODES * 16) / B;                  // 16-lane-per-node
    const int dgrid   = (N_NODES + B - 1) / B;               // 1-thread-per-node
    const int pgrid   = (N_NODES / NPW * 64) / B;            // NPW-nodes-per-wave

    hipMemsetAsync(cnt, 0, 2 * N_NODES * sizeof(int), stream);  // cnt + deg

    hist_mlp<<<egrid, B, 0, stream>>>(
        edge_attr, ew, w1, b1, w2, b2, edge_index, cnt, deg, rank, epair);

    scan_partial<<<SCAN_NB, SCAN_B, 0, stream>>>(cnt, part);
    scan_offsets<<<1, 256, 0, stream>>>(part, baseoff);
    scan_apply<<<SCAN_NB, SCAN_B, 0, stream>>>(cnt, baseoff, row_ptr);

    make_dinv<<<dgrid, B, 0, stream>>>(deg, dinv, row_ptr, csr_pair);

    scatter_perm<<<egrid, B, 0, stream>>>(edge_index, rank, row_ptr, perm);

    pair_build<<<ngrid16, B, 0, stream>>>(
        row_ptr, cnt, perm, epair, dinv, csr_pair);

    init_x<<<ngrid, B, 0, stream>>>(
        user_w, artist_w, album_w, audio, artist_ids, album_ids,
        (__hip_bfloat16*)x0);

    propagate_mid<<<pgrid, B, 0, stream>>>(row_ptr, csr_pair, x0, x1);
    propagate_mid<<<pgrid, B, 0, stream>>>(row_ptr, csr_pair, x1, x2);
    propagate_final<<<pgrid, B, 0, stream>>>(row_ptr, csr_pair, x0, x1, x2, out);
}

// Round 6
// 421.926 us; speedup vs baseline: 1.1083x; 1.1083x over previous
//
#include <hip/hip_runtime.h>
#include <hip/hip_bf16.h>
#include <math.h>

#define NUM_USERS  100000
#define NUM_ITEMS  50000
#define N_NODES    150000
#define EMBED_DIM  64
#define NUM_EDGES  1250000
#define MLP_HID    32
#define SCAN_B     1024
#define SCAN_NB    ((N_NODES + SCAN_B - 1) / SCAN_B)   // 147
#define NPW        4                                   // nodes per wave
#define PAD(x)     (((x) + 15) & ~15)                  // segment pad to 16

// ---------------------------------------------------------------------------
// hist + per-edge MLP fused, 2 EDGES PER THREAD (2 independent atomics in
// flight per lane -> 2x memory-level parallelism on the random-RMW path).
// rank via int atomicAdd (rank IS the CSR slot), epair[e]={src,w} streaming.
// NO deg atomic (deg is computed in pair_build's fused segment sum).
// ---------------------------------------------------------------------------
__global__ void hist_mlp(const float* __restrict__ edge_attr,
                         const float* __restrict__ ew,
                         const float* __restrict__ w1,
                         const float* __restrict__ b1,
                         const float* __restrict__ w2,
                         const float* __restrict__ b2,
                         const int*   __restrict__ edge_index,
                         int*   __restrict__ cnt,
                         int*   __restrict__ rank,
                         int2*  __restrict__ epair) {
    __shared__ float w1s[8 * MLP_HID];
    __shared__ float b1s[MLP_HID];
    __shared__ float w2s[MLP_HID];
    int tid = threadIdx.x;
    if (tid < 8 * MLP_HID) w1s[tid] = w1[tid];
    if (tid < MLP_HID) { b1s[tid] = b1[tid]; w2s[tid] = w2[tid]; }
    __syncthreads();

    int t = blockIdx.x * blockDim.x + tid;
    int e0 = 2 * t;                 // NUM_EDGES is even -> e0,e1 both valid
    int e1 = 2 * t + 1;
    if (e0 >= NUM_EDGES) return;

    int c0 = edge_index[NUM_EDGES + e0];
    int c1 = edge_index[NUM_EDGES + e1];
    int r0 = atomicAdd(&cnt[c0], 1);     // two independent RMWs in flight
    int r1 = atomicAdd(&cnt[c1], 1);

    float ef0[8], ef1[8];
#pragma unroll
    for (int k = 0; k < 7; ++k) ef0[k] = edge_attr[e0 * 7 + k];
#pragma unroll
    for (int k = 0; k < 7; ++k) ef1[k] = edge_attr[e1 * 7 + k];
    ef0[7] = ew[e0];
    ef1[7] = ew[e1];

    float s0 = b2[0], s1 = b2[0];
#pragma unroll
    for (int j = 0; j < MLP_HID; ++j) {
        float h0 = b1s[j], h1 = b1s[j];
#pragma unroll
        for (int k = 0; k < 8; ++k) {
            float wv = w1s[k * MLP_HID + j];
            h0 = fmaf(ef0[k], wv, h0);
            h1 = fmaf(ef1[k], wv, h1);
        }
        h0 = fmaxf(h0, 0.0f);
        h1 = fmaxf(h1, 0.0f);
        float w2v = w2s[j];
        s0 = fmaf(h0, w2v, s0);
        s1 = fmaf(h1, w2v, s1);
    }
    float wa = 1.0f / (1.0f + expf(-s0));
    float wb = 1.0f / (1.0f + expf(-s1));

    rank[e0] = r0;
    rank[e1] = r1;
    int2 pr0; pr0.x = edge_index[e0]; pr0.y = __float_as_int(wa);
    int2 pr1; pr1.x = edge_index[e1]; pr1.y = __float_as_int(wb);
    epair[e0] = pr0;                // streaming, coalesced (8B pairs)
    epair[e1] = pr1;
}

// ---------------------------------------------------------------------------
// Device-wide exclusive scan of PAD16(cnt) -> row_ptr, 3 phases.
// ---------------------------------------------------------------------------
__global__ void scan_partial(const int* __restrict__ cnt,
                             int* __restrict__ part) {
    __shared__ int s[SCAN_B];
    int tid = threadIdx.x;
    int i = blockIdx.x * SCAN_B + tid;
    s[tid] = (i < N_NODES) ? PAD(cnt[i]) : 0;
    __syncthreads();
#pragma unroll
    for (int off = SCAN_B / 2; off > 0; off >>= 1) {
        if (tid < off) s[tid] += s[tid + off];
        __syncthreads();
    }
    if (tid == 0) part[blockIdx.x] = s[0];
}

__global__ void scan_offsets(const int* __restrict__ part,
                             int* __restrict__ base_off) {
    __shared__ int s[256];
    int tid = threadIdx.x;
    int v = (tid < SCAN_NB) ? part[tid] : 0;
    s[tid] = v;
    __syncthreads();
#pragma unroll
    for (int off = 1; off < 256; off <<= 1) {
        int t = (tid >= off) ? s[tid - off] : 0;
        __syncthreads();
        s[tid] += t;
        __syncthreads();
    }
    if (tid < SCAN_NB) base_off[tid] = s[tid] - v;   // exclusive
}

__global__ void scan_apply(const int* __restrict__ cnt,
                           const int* __restrict__ base_off,
                           int* __restrict__ row_ptr) {
    __shared__ int s[SCAN_B];
    int tid = threadIdx.x;
    int i = blockIdx.x * SCAN_B + tid;
    int v = (i < N_NODES) ? PAD(cnt[i]) : 0;
    s[tid] = v;
    __syncthreads();
    for (int off = 1; off < SCAN_B; off <<= 1) {
        int t = (tid >= off) ? s[tid - off] : 0;
        __syncthreads();
        s[tid] += t;
        __syncthreads();
    }
    if (i < N_NODES) row_ptr[i] = s[tid] - v + base_off[blockIdx.x];
    if (i == N_NODES - 1) row_ptr[N_NODES] = s[tid] + base_off[blockIdx.x];
}

// ---------------------------------------------------------------------------
// perm[row_ptr[c] + rank[e]] = e   — 4 edges/thread (4 scatters in flight).
// ---------------------------------------------------------------------------
__global__ void scatter_perm(const int* __restrict__ edge_index,
                             const int* __restrict__ rank,
                             const int* __restrict__ row_ptr,
                             int* __restrict__ perm) {
    int t = blockIdx.x * blockDim.x + threadIdx.x;
    int e = 4 * t;                  // NUM_EDGES % 4 == 0
    if (e >= NUM_EDGES) return;
#pragma unroll
    for (int q = 0; q < 4; ++q) {
        int c = edge_index[NUM_EDGES + e + q];
        perm[row_ptr[c] + rank[e + q]] = e + q;
    }
}

// ---------------------------------------------------------------------------
// Build padded CSR in GATHER mode (streaming fully-dirty writes), zero pads
// inline, FUSED deg -> dinv (node-major, 16 lanes/node).  Last node zeroes
// the 64-pair tail so the propagate pipeline's overrun reads are benign.
// ---------------------------------------------------------------------------
__global__ void pair_build(const int* __restrict__ row_ptr,
                           const int* __restrict__ cnt,
                           const int* __restrict__ perm,
                           const int2* __restrict__ epair,
                           int2* __restrict__ csr_pair,
                           float* __restrict__ dinv) {
    int t = blockIdx.x * blockDim.x + threadIdx.x;
    int node = t >> 4;
    int lane = t & 15;
    if (node >= N_NODES) return;
    int s = row_ptr[node];
    int e = row_ptr[node + 1];
    int re = s + cnt[node];
    float sum = 0.0f;
    for (int j = s + lane; j < e; j += 16) {
        int2 pr;
        if (j < re) {
            int eid = perm[j];
            pr = epair[eid];
            sum += __int_as_float(pr.y);
        } else {
            pr.x = 0; pr.y = 0;
        }
        csr_pair[j] = pr;
    }
    sum += __shfl_xor(sum, 8);
    sum += __shfl_xor(sum, 4);
    sum += __shfl_xor(sum, 2);
    sum += __shfl_xor(sum, 1);
    if (lane == 0)
        dinv[node] = (sum > 0.0f) ? rsqrtf(fmaxf(sum, 1e-30f)) : 0.0f;
    if (node == N_NODES - 1) {
        int2 z; z.x = 0; z.y = 0;
        for (int q = lane; q < 64; q += 16) csr_pair[e + q] = z;
    }
}

// ---------------------------------------------------------------------------
// Streaming prescale over padded CSR: pair.w *= dinv[node] * dinv[pair.src].
// Pads have w=0 -> stay 0 (unconditional loop, no cnt load).
// dinv is 600KB, L2-hot; the pass is ~19MB R + ~19MB W streaming.
// ---------------------------------------------------------------------------
__global__ void csr_scale_pad(const int* __restrict__ row_ptr,
                              const float* __restrict__ dinv,
                              int2* __restrict__ csr_pair) {
    int t = blockIdx.x * blockDim.x + threadIdx.x;
    int node = t >> 4;
    int lane = t & 15;
    if (node >= N_NODES) return;
    int s = row_ptr[node], e = row_ptr[node + 1];
    float dc = dinv[node];
    for (int j = s + lane; j < e; j += 16) {
        int2 p = csr_pair[j];
        p.y = __float_as_int(__int_as_float(p.y) * dc * dinv[p.x]);
        csr_pair[j] = p;
    }
}

// ---------------------------------------------------------------------------
// build x0: bf16 only.
// ---------------------------------------------------------------------------
__global__ void init_x(const float* __restrict__ user_w,
                       const float* __restrict__ artist_w,
                       const float* __restrict__ album_w,
                       const float* __restrict__ audio,
                       const int*   __restrict__ artist_ids,
                       const int*   __restrict__ album_ids,
                       __hip_bfloat16* __restrict__ x) {
    int t = blockIdx.x * blockDim.x + threadIdx.x;
    int row = t >> 6;
    int lane = t & 63;
    if (row >= N_NODES) return;

    float v;
    if (row < NUM_USERS) {
        v = user_w[row * EMBED_DIM + lane];
    } else {
        int r = row - NUM_USERS;
        int ar = artist_ids[r];
        int al = album_ids[r];
        v = audio[r * EMBED_DIM + lane]
          + 0.5f * (artist_w[ar * EMBED_DIM + lane] + album_w[al * EMBED_DIM + lane]);
    }
    float ss = v * v;
#pragma unroll
    for (int off = 32; off > 0; off >>= 1) ss += __shfl_xor(ss, off);
    float scale = 1.0f / fmaxf(sqrtf(ss), 1e-12f);
    x[row * EMBED_DIM + lane] = __float2bfloat16(v * scale);
}

// ---------------------------------------------------------------------------
// pull-mode propagation v6 (unchanged from round 5): NPW(4) nodes/wave,
// pad-16 CSR, software-pipelined flat group stream; weights fully prescaled.
// ---------------------------------------------------------------------------
#define BF_LO(u) __uint_as_float((u) << 16)
#define BF_HI(u) __uint_as_float((u) & 0xffff0000u)

#define REDUCE_ACC()                                                         \
    a0 += __shfl_xor(a0, 16); a1 += __shfl_xor(a1, 16);                      \
    a2 += __shfl_xor(a2, 16); a3 += __shfl_xor(a3, 16);                      \
    a0 += __shfl_xor(a0, 32); a1 += __shfl_xor(a1, 32);                      \
    a2 += __shfl_xor(a2, 32); a3 += __shfl_xor(a3, 32)

#define NEXT_BOUND() ((k == 1) ? rs2 : (k == 2) ? rs3 : rs4)

__global__ void propagate_mid(const int* __restrict__ row_ptr,
                              const int2* __restrict__ csr_pair,
                              const unsigned short* __restrict__ xin,
                              unsigned short* __restrict__ xout) {
    int wave = (blockIdx.x * blockDim.x + threadIdx.x) >> 6;
    int lane = threadIdx.x & 63;
    int node0 = wave * NPW;
    if (node0 >= N_NODES) return;

    int eg = lane >> 4;          // edge slot group 0..3 (4 edges each)
    int dq = (lane & 15) << 2;   // dim quad start

    int rpv = row_ptr[node0 + (lane <= NPW ? lane : NPW)];
    int rs0 = __shfl(rpv, 0);
    int rs1 = __shfl(rpv, 1);
    int rs2 = __shfl(rpv, 2);
    int rs3 = __shfl(rpv, 3);
    int rs4 = __shfl(rpv, 4);

    float a0 = 0, a1 = 0, a2 = 0, a3 = 0;
    int k = 0;
    int bnext = rs1;

#define STORE_MID()                                                          \
    do {                                                                     \
        if (eg == 0) {                                                       \
            size_t o = ((size_t)(node0 + k) << 6) + dq;                      \
            unsigned int b0 = (unsigned int)__bfloat16_as_ushort(__float2bfloat16(a0)); \
            unsigned int b1 = (unsigned int)__bfloat16_as_ushort(__float2bfloat16(a1)); \
            unsigned int b2 = (unsigned int)__bfloat16_as_ushort(__float2bfloat16(a2)); \
            unsigned int b3 = (unsigned int)__bfloat16_as_ushort(__float2bfloat16(a3)); \
            uint2 u;                                                         \
            u.x = b0 | (b1 << 16);                                           \
            u.y = b2 | (b3 << 16);                                           \
            *(uint2*)(xout + o) = u;                                         \
        }                                                                    \
    } while (0)

    // leading empty nodes
    while (k < NPW && rs0 == bnext) {
        STORE_MID();               // acc is zero
        ++k;
        bnext = NEXT_BOUND();
    }

    // pipeline prologue
    int j = rs0 + (eg << 2);
    int2 pa0 = csr_pair[j],      pa1 = csr_pair[j + 1];
    int2 pa2 = csr_pair[j + 2],  pa3 = csr_pair[j + 3];
    uint2 ua0 = *(const uint2*)(xin + ((size_t)pa0.x << 6) + dq);
    uint2 ua1 = *(const uint2*)(xin + ((size_t)pa1.x << 6) + dq);
    uint2 ua2 = *(const uint2*)(xin + ((size_t)pa2.x << 6) + dq);
    uint2 ua3 = *(const uint2*)(xin + ((size_t)pa3.x << 6) + dq);
    int2 pb0 = csr_pair[j + 16], pb1 = csr_pair[j + 17];
    int2 pb2 = csr_pair[j + 18], pb3 = csr_pair[j + 19];

    for (int base = rs0; base < rs4; base += 16) {
        // issue next group's gathers (guard overrun to row 0)
        bool live = (base + 16) < rs4;
        int sb0 = live ? pb0.x : 0;
        int sb1 = live ? pb1.x : 0;
        int sb2 = live ? pb2.x : 0;
        int sb3 = live ? pb3.x : 0;
        uint2 ub0 = *(const uint2*)(xin + ((size_t)sb0 << 6) + dq);
        uint2 ub1 = *(const uint2*)(xin + ((size_t)sb1 << 6) + dq);
        uint2 ub2 = *(const uint2*)(xin + ((size_t)sb2 << 6) + dq);
        uint2 ub3 = *(const uint2*)(xin + ((size_t)sb3 << 6) + dq);
        // load pairs two groups ahead
        int2 pc0 = csr_pair[j + 32], pc1 = csr_pair[j + 33];
        int2 pc2 = csr_pair[j + 34], pc3 = csr_pair[j + 35];

        // FMA current group (gathers issued one full iteration ago)
        float w0 = __int_as_float(pa0.y);
        float w1 = __int_as_float(pa1.y);
        float w2 = __int_as_float(pa2.y);
        float w3 = __int_as_float(pa3.y);
        a0 = fmaf(w0, BF_LO(ua0.x), a0); a1 = fmaf(w0, BF_HI(ua0.x), a1);
        a2 = fmaf(w0, BF_LO(ua0.y), a2); a3 = fmaf(w0, BF_HI(ua0.y), a3);
        a0 = fmaf(w1, BF_LO(ua1.x), a0); a1 = fmaf(w1, BF_HI(ua1.x), a1);
        a2 = fmaf(w1, BF_LO(ua1.y), a2); a3 = fmaf(w1, BF_HI(ua1.y), a3);
        a0 = fmaf(w2, BF_LO(ua2.x), a0); a1 = fmaf(w2, BF_HI(ua2.x), a1);
        a2 = fmaf(w2, BF_LO(ua2.y), a2); a3 = fmaf(w2, BF_HI(ua2.y), a3);
        a0 = fmaf(w3, BF_LO(ua3.x), a0); a1 = fmaf(w3, BF_HI(ua3.x), a1);
        a2 = fmaf(w3, BF_LO(ua3.y), a2); a3 = fmaf(w3, BF_HI(ua3.y), a3);

        // rotate pipeline registers
        pa0 = pb0; pa1 = pb1; pa2 = pb2; pa3 = pb3;
        pb0 = pc0; pb1 = pc1; pb2 = pc2; pb3 = pc3;
        ua0 = ub0; ua1 = ub1; ua2 = ub2; ua3 = ub3;
        j += 16;

        // node boundary (wave-uniform)
        int pos = base + 16;
        while (k < NPW && pos == bnext) {
            REDUCE_ACC();
            STORE_MID();
            a0 = 0; a1 = 0; a2 = 0; a3 = 0;
            ++k;
            bnext = NEXT_BOUND();
        }
    }
#undef STORE_MID
}

// ---------------------------------------------------------------------------
// FINAL layer: gather from x2, then out = l2norm((x0+x1+x2+a)/4), f32.
// ---------------------------------------------------------------------------
__global__ void propagate_final(const int* __restrict__ row_ptr,
                                const int2* __restrict__ csr_pair,
                                const unsigned short* __restrict__ x0,
                                const unsigned short* __restrict__ x1,
                                const unsigned short* __restrict__ x2,
                                float* __restrict__ outp) {
    int wave = (blockIdx.x * blockDim.x + threadIdx.x) >> 6;
    int lane = threadIdx.x & 63;
    int node0 = wave * NPW;
    if (node0 >= N_NODES) return;

    int eg = lane >> 4;
    int dq = (lane & 15) << 2;

    int rpv = row_ptr[node0 + (lane <= NPW ? lane : NPW)];
    int rs0 = __shfl(rpv, 0);
    int rs1 = __shfl(rpv, 1);
    int rs2 = __shfl(rpv, 2);
    int rs3 = __shfl(rpv, 3);
    int rs4 = __shfl(rpv, 4);

    float a0 = 0, a1 = 0, a2 = 0, a3 = 0;
    int k = 0;
    int bnext = rs1;

#define STORE_FIN()                                                          \
    do {                                                                     \
        if (eg == 0) {                                                       \
            size_t o = ((size_t)(node0 + k) << 6) + dq;                      \
            uint2 u0 = *(const uint2*)(x0 + o);                              \
            uint2 u1 = *(const uint2*)(x1 + o);                              \
            uint2 u2 = *(const uint2*)(x2 + o);                              \
            float v0 = (BF_LO(u0.x) + BF_LO(u1.x) + BF_LO(u2.x) + a0) * 0.25f; \
            float v1 = (BF_HI(u0.x) + BF_HI(u1.x) + BF_HI(u2.x) + a1) * 0.25f; \
            float v2 = (BF_LO(u0.y) + BF_LO(u1.y) + BF_LO(u2.y) + a2) * 0.25f; \
            float v3 = (BF_HI(u0.y) + BF_HI(u1.y) + BF_HI(u2.y) + a3) * 0.25f; \
            float ss = v0 * v0 + v1 * v1 + v2 * v2 + v3 * v3;                \
            ss += __shfl_xor(ss, 1);                                         \
            ss += __shfl_xor(ss, 2);                                         \
            ss += __shfl_xor(ss, 4);                                         \
            ss += __shfl_xor(ss, 8);                                         \
            float scale = 1.0f / fmaxf(sqrtf(ss), 1e-12f);                   \
            float4 r = { v0 * scale, v1 * scale, v2 * scale, v3 * scale };   \
            *(float4*)(outp + o) = r;                                        \
        }                                                                    \
    } while (0)

    while (k < NPW && rs0 == bnext) {
        STORE_FIN();
        ++k;
        bnext = NEXT_BOUND();
    }

    int j = rs0 + (eg << 2);
    int2 pa0 = csr_pair[j],      pa1 = csr_pair[j + 1];
    int2 pa2 = csr_pair[j + 2],  pa3 = csr_pair[j + 3];
    uint2 ua0 = *(const uint2*)(x2 + ((size_t)pa0.x << 6) + dq);
    uint2 ua1 = *(const uint2*)(x2 + ((size_t)pa1.x << 6) + dq);
    uint2 ua2 = *(const uint2*)(x2 + ((size_t)pa2.x << 6) + dq);
    uint2 ua3 = *(const uint2*)(x2 + ((size_t)pa3.x << 6) + dq);
    int2 pb0 = csr_pair[j + 16], pb1 = csr_pair[j + 17];
    int2 pb2 = csr_pair[j + 18], pb3 = csr_pair[j + 19];

    for (int base = rs0; base < rs4; base += 16) {
        bool live = (base + 16) < rs4;
        int sb0 = live ? pb0.x : 0;
        int sb1 = live ? pb1.x : 0;
        int sb2 = live ? pb2.x : 0;
        int sb3 = live ? pb3.x : 0;
        uint2 ub0 = *(const uint2*)(x2 + ((size_t)sb0 << 6) + dq);
        uint2 ub1 = *(const uint2*)(x2 + ((size_t)sb1 << 6) + dq);
        uint2 ub2 = *(const uint2*)(x2 + ((size_t)sb2 << 6) + dq);
        uint2 ub3 = *(const uint2*)(x2 + ((size_t)sb3 << 6) + dq);
        int2 pc0 = csr_pair[j + 32], pc1 = csr_pair[j + 33];
        int2 pc2 = csr_pair[j + 34], pc3 = csr_pair[j + 35];

        float w0 = __int_as_float(pa0.y);
        float w1 = __int_as_float(pa1.y);
        float w2 = __int_as_float(pa2.y);
        float w3 = __int_as_float(pa3.y);
        a0 = fmaf(w0, BF_LO(ua0.x), a0); a1 = fmaf(w0, BF_HI(ua0.x), a1);
        a2 = fmaf(w0, BF_LO(ua0.y), a2); a3 = fmaf(w0, BF_HI(ua0.y), a3);
        a0 = fmaf(w1, BF_LO(ua1.x), a0); a1 = fmaf(w1, BF_HI(ua1.x), a1);
        a2 = fmaf(w1, BF_LO(ua1.y), a2); a3 = fmaf(w1, BF_HI(ua1.y), a3);
        a0 = fmaf(w2, BF_LO(ua2.x), a0); a1 = fmaf(w2, BF_HI(ua2.x), a1);
        a2 = fmaf(w2, BF_LO(ua2.y), a2); a3 = fmaf(w2, BF_HI(ua2.y), a3);
        a0 = fmaf(w3, BF_LO(ua3.x), a0); a1 = fmaf(w3, BF_HI(ua3.x), a1);
        a2 = fmaf(w3, BF_LO(ua3.y), a2); a3 = fmaf(w3, BF_HI(ua3.y), a3);

        pa0 = pb0; pa1 = pb1; pa2 = pb2; pa3 = pb3;
        pb0 = pc0; pb1 = pc1; pb2 = pc2; pb3 = pc3;
        ua0 = ub0; ua1 = ub1; ua2 = ub2; ua3 = ub3;
        j += 16;

        int pos = base + 16;
        while (k < NPW && pos == bnext) {
            REDUCE_ACC();
            STORE_FIN();
            a0 = 0; a1 = 0; a2 = 0; a3 = 0;
            ++k;
            bnext = NEXT_BOUND();
        }
    }
#undef STORE_FIN
    if (blockIdx.x == 0 && threadIdx.x == 0)
        outp[(size_t)N_NODES * EMBED_DIM] = 0.0f;  // align_loss
}

#undef BF_LO
#undef BF_HI

// ---------------------------------------------------------------------------
extern "C" void kernel_launch(void* const* d_in, const int* in_sizes, int n_in,
                              void* d_out, int out_size, void* d_ws, size_t ws_size,
                              hipStream_t stream) {
    const float* user_w     = (const float*)d_in[0];
    const float* artist_w   = (const float*)d_in[1];
    const float* album_w    = (const float*)d_in[2];
    const float* audio      = (const float*)d_in[3];
    const float* edge_attr  = (const float*)d_in[4];
    const float* ew         = (const float*)d_in[5];
    const float* w1         = (const float*)d_in[6];
    const float* b1         = (const float*)d_in[7];
    const float* w2         = (const float*)d_in[8];
    const float* b2         = (const float*)d_in[9];
    const int*   edge_index = (const int*)d_in[10];
    const int*   artist_ids = (const int*)d_in[11];
    const int*   album_ids  = (const int*)d_in[12];
    float* out = (float*)d_out;

    float* ws = (float*)d_ws;
    // Persistent regions (float-unit offsets):
    unsigned short* x0 = (unsigned short*)ws;                // 9.6M bf16 (0..4.8M)
    unsigned short* x1 = (unsigned short*)(ws + 4800000);    // 9.6M bf16
    unsigned short* x2 = (unsigned short*)(ws + 9600000);    // 9.6M bf16
    float* dinv    = ws + 14400000;                          // 150k floats
    int*  row_ptr  = (int*)(ws + 14560000);                  // 150001 ints
    int2* csr_pair = (int2*)(ws + 14720000);                 // padded-16 CSR
                                                             // (<=2.6M pairs
                                                             // + 64 tail)
    // Transients aliased into x0/x1 region (dead before init_x / propagate):
    int*   cnt     = (int*)ws;                               // 150k ints
    int*   rank    = (int*)(ws + 150000);                    // 1.25M ints
    int*   part    = (int*)(ws + 1600000);                   // 147 ints
    int*   baseoff = (int*)(ws + 1601000);                   // 147 ints
    int2*  epair   = (int2*)(ws + 1700000);                  // 1.25M pairs
    int*   perm    = (int*)(ws + 4800000);                   // <=2.6M ints (x1)

    const int B = 256;
    const int egrid2  = (NUM_EDGES / 2 + B - 1) / B;         // 2 edges/thread
    const int egrid4  = (NUM_EDGES / 4 + B - 1) / B;         // 4 edges/thread
    const int ngrid   = (N_NODES * EMBED_DIM) / B;           // wave-per-node
    const int ngrid16 = (N_NODES * 16) / B;                  // 16-lane-per-node
    const int pgrid   = (N_NODES / NPW * 64) / B;            // NPW-nodes-per-wave

    hipMemsetAsync(cnt, 0, N_NODES * sizeof(int), stream);

    hist_mlp<<<egrid2, B, 0, stream>>>(
        edge_attr, ew, w1, b1, w2, b2, edge_index, cnt, rank, epair);

    scan_partial<<<SCAN_NB, SCAN_B, 0, stream>>>(cnt, part);
    scan_offsets<<<1, 256, 0, stream>>>(part, baseoff);
    scan_apply<<<SCAN_NB, SCAN_B, 0, stream>>>(cnt, baseoff, row_ptr);

    scatter_perm<<<egrid4, B, 0, stream>>>(edge_index, rank, row_ptr, perm);

    pair_build<<<ngrid16, B, 0, stream>>>(
        row_ptr, cnt, perm, epair, csr_pair, dinv);

    csr_scale_pad<<<ngrid16, B, 0, stream>>>(row_ptr, dinv, csr_pair);

    init_x<<<ngrid, B, 0, stream>>>(
        user_w, artist_w, album_w, audio, artist_ids, album_ids,
        (__hip_bfloat16*)x0);

    propagate_mid<<<pgrid, B, 0, stream>>>(row_ptr, csr_pair, x0, x1);
    propagate_mid<<<pgrid, B, 0, stream>>>(row_ptr, csr_pair, x1, x2);
    propagate_final<<<pgrid, B, 0, stream>>>(row_ptr, csr_pair, x0, x1, x2, out);
}

// Round 8
// 401.046 us; speedup vs baseline: 1.1660x; 1.0521x over previous
//
#include <hip/hip_runtime.h>
#include <hip/hip_bf16.h>
#include <math.h>

#define NUM_USERS  100000
#define NUM_ITEMS  50000
#define N_NODES    150000
#define EMBED_DIM  64
#define NUM_EDGES  1250000
#define MLP_HID    32
#define SCAN_B     1024
#define SCAN_NB    ((N_NODES + SCAN_B - 1) / SCAN_B)   // 147
#define NPW        4                                   // nodes per wave
#define PAD(x)     (((x) + 15) & ~15)                  // segment pad to 16

// ---------------------------------------------------------------------------
// hist + per-edge MLP fused, 1 edge/thread (best measured occupancy 72%).
// rank via int atomicAdd (rank IS the CSR slot), epair[e]={src,w} streaming.
// No deg atomic — deg comes from pair_build's fused segment sum.
// ---------------------------------------------------------------------------
__global__ void hist_mlp(const float* __restrict__ edge_attr,
                         const float* __restrict__ ew,
                         const float* __restrict__ w1,
                         const float* __restrict__ b1,
                         const float* __restrict__ w2,
                         const float* __restrict__ b2,
                         const int*   __restrict__ edge_index,
                         int*   __restrict__ cnt,
                         int*   __restrict__ rank,
                         int2*  __restrict__ epair) {
    __shared__ float w1s[8 * MLP_HID];
    __shared__ float b1s[MLP_HID];
    __shared__ float w2s[MLP_HID];
    int tid = threadIdx.x;
    if (tid < 8 * MLP_HID) w1s[tid] = w1[tid];
    if (tid < MLP_HID) { b1s[tid] = b1[tid]; w2s[tid] = w2[tid]; }
    __syncthreads();

    int e = blockIdx.x * blockDim.x + tid;
    if (e >= NUM_EDGES) return;

    int c = edge_index[NUM_EDGES + e];
    rank[e] = atomicAdd(&cnt[c], 1);

    float ef[8];
#pragma unroll
    for (int k = 0; k < 7; ++k) ef[k] = edge_attr[e * 7 + k];
    ef[7] = ew[e];

    float s = b2[0];
#pragma unroll
    for (int j = 0; j < MLP_HID; ++j) {
        float h = b1s[j];
#pragma unroll
        for (int k = 0; k < 8; ++k) h = fmaf(ef[k], w1s[k * MLP_HID + j], h);
        h = fmaxf(h, 0.0f);
        s = fmaf(h, w2s[j], s);
    }
    float w = 1.0f / (1.0f + expf(-s));

    int2 pr;
    pr.x = edge_index[e];          // src row
    pr.y = __float_as_int(w);      // RAW weight (no dinv scaling anywhere)
    epair[e] = pr;                 // streaming, coalesced
}

// ---------------------------------------------------------------------------
// Device-wide exclusive scan of PAD16(cnt) -> row_ptr, 3 phases.
// ---------------------------------------------------------------------------
__global__ void scan_partial(const int* __restrict__ cnt,
                             int* __restrict__ part) {
    __shared__ int s[SCAN_B];
    int tid = threadIdx.x;
    int i = blockIdx.x * SCAN_B + tid;
    s[tid] = (i < N_NODES) ? PAD(cnt[i]) : 0;
    __syncthreads();
#pragma unroll
    for (int off = SCAN_B / 2; off > 0; off >>= 1) {
        if (tid < off) s[tid] += s[tid + off];
        __syncthreads();
    }
    if (tid == 0) part[blockIdx.x] = s[0];
}

__global__ void scan_offsets(const int* __restrict__ part,
                             int* __restrict__ base_off) {
    __shared__ int s[256];
    int tid = threadIdx.x;
    int v = (tid < SCAN_NB) ? part[tid] : 0;
    s[tid] = v;
    __syncthreads();
#pragma unroll
    for (int off = 1; off < 256; off <<= 1) {
        int t = (tid >= off) ? s[tid - off] : 0;
        __syncthreads();
        s[tid] += t;
        __syncthreads();
    }
    if (tid < SCAN_NB) base_off[tid] = s[tid] - v;   // exclusive
}

__global__ void scan_apply(const int* __restrict__ cnt,
                           const int* __restrict__ base_off,
                           int* __restrict__ row_ptr) {
    __shared__ int s[SCAN_B];
    int tid = threadIdx.x;
    int i = blockIdx.x * SCAN_B + tid;
    int v = (i < N_NODES) ? PAD(cnt[i]) : 0;
    s[tid] = v;
    __syncthreads();
    for (int off = 1; off < SCAN_B; off <<= 1) {
        int t = (tid >= off) ? s[tid - off] : 0;
        __syncthreads();
        s[tid] += t;
        __syncthreads();
    }
    if (i < N_NODES) row_ptr[i] = s[tid] - v + base_off[blockIdx.x];
    if (i == N_NODES - 1) row_ptr[N_NODES] = s[tid] + base_off[blockIdx.x];
}

// ---------------------------------------------------------------------------
// perm[row_ptr[c] + rank[e]] = e   — 4 edges/thread (4 scatters in flight).
// ---------------------------------------------------------------------------
__global__ void scatter_perm(const int* __restrict__ edge_index,
                             const int* __restrict__ rank,
                             const int* __restrict__ row_ptr,
                             int* __restrict__ perm) {
    int t = blockIdx.x * blockDim.x + threadIdx.x;
    int e = 4 * t;                  // NUM_EDGES % 4 == 0
    if (e >= NUM_EDGES) return;
#pragma unroll
    for (int q = 0; q < 4; ++q) {
        int c = edge_index[NUM_EDGES + e + q];
        perm[row_ptr[c] + rank[e + q]] = e + q;
    }
}

// ---------------------------------------------------------------------------
// Build padded CSR in GATHER mode (streaming fully-dirty writes, RAW w),
// zero pads inline, FUSED deg -> dinv, dinv2 = dinv^2, rd = 1/dinv.
// Last node zeroes a 64-pair tail for the propagate prefetch overrun.
// ---------------------------------------------------------------------------
__global__ void pair_build(const int* __restrict__ row_ptr,
                           const int* __restrict__ cnt,
                           const int* __restrict__ perm,
                           const int2* __restrict__ epair,
                           int2* __restrict__ csr_pair,
                           float* __restrict__ dinv,
                           float* __restrict__ dinv2,
                           float* __restrict__ rd) {
    int t = blockIdx.x * blockDim.x + threadIdx.x;
    int node = t >> 4;
    int lane = t & 15;
    if (node >= N_NODES) return;
    int s = row_ptr[node];
    int e = row_ptr[node + 1];
    int re = s + cnt[node];
    float sum = 0.0f;
    for (int j = s + lane; j < e; j += 16) {
        int2 pr;
        if (j < re) {
            int eid = perm[j];
            pr = epair[eid];
            sum += __int_as_float(pr.y);
        } else {
            pr.x = 0; pr.y = 0;
        }
        csr_pair[j] = pr;
    }
    sum += __shfl_xor(sum, 8);
    sum += __shfl_xor(sum, 4);
    sum += __shfl_xor(sum, 2);
    sum += __shfl_xor(sum, 1);
    if (lane == 0) {
        float dv = (sum > 0.0f) ? rsqrtf(fmaxf(sum, 1e-30f)) : 0.0f;
        dinv[node]  = dv;
        dinv2[node] = dv * dv;
        rd[node]    = (dv > 0.0f) ? (1.0f / dv) : 0.0f;
    }
    if (node == N_NODES - 1) {
        int2 z; z.x = 0; z.y = 0;
        for (int q = lane; q < 64; q += 16) csr_pair[e + q] = z;
    }
}

// ---------------------------------------------------------------------------
// build x0 (f32, parked in the OUTPUT buffer for the final merge) and
// y0 = dinv * x0 (bf16, the propagation state).
// ---------------------------------------------------------------------------
__global__ void init_x(const float* __restrict__ user_w,
                       const float* __restrict__ artist_w,
                       const float* __restrict__ album_w,
                       const float* __restrict__ audio,
                       const int*   __restrict__ artist_ids,
                       const int*   __restrict__ album_ids,
                       const float* __restrict__ dinv,
                       float* __restrict__ x0out,
                       unsigned short* __restrict__ y0) {
    int t = blockIdx.x * blockDim.x + threadIdx.x;
    int row = t >> 6;
    int lane = t & 63;
    if (row >= N_NODES) return;

    float v;
    if (row < NUM_USERS) {
        v = user_w[row * EMBED_DIM + lane];
    } else {
        int r = row - NUM_USERS;
        int ar = artist_ids[r];
        int al = album_ids[r];
        v = audio[r * EMBED_DIM + lane]
          + 0.5f * (artist_w[ar * EMBED_DIM + lane] + album_w[al * EMBED_DIM + lane]);
    }
    float ss = v * v;
#pragma unroll
    for (int off = 32; off > 0; off >>= 1) ss += __shfl_xor(ss, off);
    float scale = 1.0f / fmaxf(sqrtf(ss), 1e-12f);
    float x0 = v * scale;
    size_t o = (size_t)row * EMBED_DIM + lane;
    x0out[o] = x0;
    y0[o] = __bfloat16_as_ushort(__float2bfloat16(x0 * dinv[row]));
}

// ---------------------------------------------------------------------------
// pull-mode propagation (round-3 v4 structure — best measured): NPW(4)
// nodes/wave, GUARD-FREE pad-16 inner loop, 4 independent uint2 gathers per
// iteration, pair pointer advances j += 16 across node boundaries.
// State is y = dinv*x; CSR holds RAW w; store applies node-uniform dinv^2.
// Prefetch overruns <=20 pairs past padded end (zeroed 64-pair tail).
// ---------------------------------------------------------------------------
#define BF_LO(u) __uint_as_float((u) << 16)
#define BF_HI(u) __uint_as_float((u) & 0xffff0000u)

__global__ void propagate_mid(const int* __restrict__ row_ptr,
                              const int2* __restrict__ csr_pair,
                              const float* __restrict__ dinv2,
                              const unsigned short* __restrict__ yin,
                              unsigned short* __restrict__ yout) {
    int wave = (blockIdx.x * blockDim.x + threadIdx.x) >> 6;
    int lane = threadIdx.x & 63;
    int node0 = wave * NPW;
    if (node0 >= N_NODES) return;

    int eg = lane >> 4;          // edge slot 0..3 (owns 4 consecutive edges)
    int dq = (lane & 15) << 2;   // dim quad start

    int rpv = row_ptr[node0 + (lane <= NPW ? lane : NPW)];
    int rs0 = __shfl(rpv, 0);
    int rs1 = __shfl(rpv, 1);
    int rs2 = __shfl(rpv, 2);
    int rs3 = __shfl(rpv, 3);
    int rs4 = __shfl(rpv, 4);

    int j = rs0 + (eg << 2);
    int2 pa0 = csr_pair[j];
    int2 pa1 = csr_pair[j + 1];
    int2 pa2 = csr_pair[j + 2];
    int2 pa3 = csr_pair[j + 3];

#pragma unroll
    for (int k = 0; k < NPW; ++k) {
        int bs = (k == 0) ? rs0 : (k == 1) ? rs1 : (k == 2) ? rs2 : rs3;
        int be = (k == 0) ? rs1 : (k == 1) ? rs2 : (k == 2) ? rs3 : rs4;
        float a0 = 0, a1 = 0, a2 = 0, a3 = 0;

        for (int base = bs; base < be; base += 16) {
            int   s0 = pa0.x; float w0 = __int_as_float(pa0.y);
            int   s1 = pa1.x; float w1 = __int_as_float(pa1.y);
            int   s2 = pa2.x; float w2 = __int_as_float(pa2.y);
            int   s3 = pa3.x; float w3 = __int_as_float(pa3.y);

            uint2 u0 = *(const uint2*)(yin + ((size_t)s0 << 6) + dq);
            uint2 u1 = *(const uint2*)(yin + ((size_t)s1 << 6) + dq);
            uint2 u2 = *(const uint2*)(yin + ((size_t)s2 << 6) + dq);
            uint2 u3 = *(const uint2*)(yin + ((size_t)s3 << 6) + dq);

            j += 16;                       // contiguous: always next group
            pa0 = csr_pair[j];
            pa1 = csr_pair[j + 1];
            pa2 = csr_pair[j + 2];
            pa3 = csr_pair[j + 3];

            a0 = fmaf(w0, BF_LO(u0.x), a0); a1 = fmaf(w0, BF_HI(u0.x), a1);
            a2 = fmaf(w0, BF_LO(u0.y), a2); a3 = fmaf(w0, BF_HI(u0.y), a3);
            a0 = fmaf(w1, BF_LO(u1.x), a0); a1 = fmaf(w1, BF_HI(u1.x), a1);
            a2 = fmaf(w1, BF_LO(u1.y), a2); a3 = fmaf(w1, BF_HI(u1.y), a3);
            a0 = fmaf(w2, BF_LO(u2.x), a0); a1 = fmaf(w2, BF_HI(u2.x), a1);
            a2 = fmaf(w2, BF_LO(u2.y), a2); a3 = fmaf(w2, BF_HI(u2.y), a3);
            a0 = fmaf(w3, BF_LO(u3.x), a0); a1 = fmaf(w3, BF_HI(u3.x), a1);
            a2 = fmaf(w3, BF_LO(u3.y), a2); a3 = fmaf(w3, BF_HI(u3.y), a3);
        }

        a0 += __shfl_xor(a0, 16); a1 += __shfl_xor(a1, 16);
        a2 += __shfl_xor(a2, 16); a3 += __shfl_xor(a3, 16);
        a0 += __shfl_xor(a0, 32); a1 += __shfl_xor(a1, 32);
        a2 += __shfl_xor(a2, 32); a3 += __shfl_xor(a3, 32);

        if (eg == 0) {
            float dc2 = dinv2[node0 + k];   // node-uniform, L2-hot
            size_t o = ((size_t)(node0 + k) << 6) + dq;
            unsigned int b0 = (unsigned int)__bfloat16_as_ushort(__float2bfloat16(a0 * dc2));
            unsigned int b1 = (unsigned int)__bfloat16_as_ushort(__float2bfloat16(a1 * dc2));
            unsigned int b2 = (unsigned int)__bfloat16_as_ushort(__float2bfloat16(a2 * dc2));
            unsigned int b3 = (unsigned int)__bfloat16_as_ushort(__float2bfloat16(a3 * dc2));
            uint2 u;
            u.x = b0 | (b1 << 16);
            u.y = b2 | (b3 << 16);
            *(uint2*)(yout + o) = u;
        }
    }
}

// ---------------------------------------------------------------------------
// FINAL layer: a = sum w*y2[src]; x3 = dinv*a; merge with x0 (f32, parked in
// outp) and x1 = rd*y1, x2 = rd*y2; l2norm; overwrite outp.
// ---------------------------------------------------------------------------
__global__ void propagate_final(const int* __restrict__ row_ptr,
                                const int2* __restrict__ csr_pair,
                                const float* __restrict__ dinv,
                                const float* __restrict__ rd,
                                const unsigned short* __restrict__ y1,
                                const unsigned short* __restrict__ y2,
                                float* __restrict__ outp) {
    int wave = (blockIdx.x * blockDim.x + threadIdx.x) >> 6;
    int lane = threadIdx.x & 63;
    int node0 = wave * NPW;
    if (node0 >= N_NODES) return;

    int eg = lane >> 4;
    int dq = (lane & 15) << 2;

    int rpv = row_ptr[node0 + (lane <= NPW ? lane : NPW)];
    int rs0 = __shfl(rpv, 0);
    int rs1 = __shfl(rpv, 1);
    int rs2 = __shfl(rpv, 2);
    int rs3 = __shfl(rpv, 3);
    int rs4 = __shfl(rpv, 4);

    int j = rs0 + (eg << 2);
    int2 pa0 = csr_pair[j];
    int2 pa1 = csr_pair[j + 1];
    int2 pa2 = csr_pair[j + 2];
    int2 pa3 = csr_pair[j + 3];

#pragma unroll
    for (int k = 0; k < NPW; ++k) {
        int bs = (k == 0) ? rs0 : (k == 1) ? rs1 : (k == 2) ? rs2 : rs3;
        int be = (k == 0) ? rs1 : (k == 1) ? rs2 : (k == 2) ? rs3 : rs4;
        float a0 = 0, a1 = 0, a2 = 0, a3 = 0;

        for (int base = bs; base < be; base += 16) {
            int   s0 = pa0.x; float w0 = __int_as_float(pa0.y);
            int   s1 = pa1.x; float w1 = __int_as_float(pa1.y);
            int   s2 = pa2.x; float w2 = __int_as_float(pa2.y);
            int   s3 = pa3.x; float w3 = __int_as_float(pa3.y);

            uint2 u0 = *(const uint2*)(y2 + ((size_t)s0 << 6) + dq);
            uint2 u1 = *(const uint2*)(y2 + ((size_t)s1 << 6) + dq);
            uint2 u2 = *(const uint2*)(y2 + ((size_t)s2 << 6) + dq);
            uint2 u3 = *(const uint2*)(y2 + ((size_t)s3 << 6) + dq);

            j += 16;
            pa0 = csr_pair[j];
            pa1 = csr_pair[j + 1];
            pa2 = csr_pair[j + 2];
            pa3 = csr_pair[j + 3];

            a0 = fmaf(w0, BF_LO(u0.x), a0); a1 = fmaf(w0, BF_HI(u0.x), a1);
            a2 = fmaf(w0, BF_LO(u0.y), a2); a3 = fmaf(w0, BF_HI(u0.y), a3);
            a0 = fmaf(w1, BF_LO(u1.x), a0); a1 = fmaf(w1, BF_HI(u1.x), a1);
            a2 = fmaf(w1, BF_LO(u1.y), a2); a3 = fmaf(w1, BF_HI(u1.y), a3);
            a0 = fmaf(w2, BF_LO(u2.x), a0); a1 = fmaf(w2, BF_HI(u2.x), a1);
            a2 = fmaf(w2, BF_LO(u2.y), a2); a3 = fmaf(w2, BF_HI(u2.y), a3);
            a0 = fmaf(w3, BF_LO(u3.x), a0); a1 = fmaf(w3, BF_HI(u3.x), a1);
            a2 = fmaf(w3, BF_LO(u3.y), a2); a3 = fmaf(w3, BF_HI(u3.y), a3);
        }

        a0 += __shfl_xor(a0, 16); a1 += __shfl_xor(a1, 16);
        a2 += __shfl_xor(a2, 16); a3 += __shfl_xor(a3, 16);
        a0 += __shfl_xor(a0, 32); a1 += __shfl_xor(a1, 32);
        a2 += __shfl_xor(a2, 32); a3 += __shfl_xor(a3, 32);

        if (eg == 0) {
            int node = node0 + k;
            float dv  = dinv[node];
            float rdv = rd[node];
            size_t o = ((size_t)node << 6) + dq;
            float4 x0v = *(const float4*)(outp + o);
            uint2 u1v = *(const uint2*)(y1 + o);
            uint2 u2v = *(const uint2*)(y2 + o);

            float v0 = (x0v.x + rdv * (BF_LO(u1v.x) + BF_LO(u2v.x)) + dv * a0) * 0.25f;
            float v1 = (x0v.y + rdv * (BF_HI(u1v.x) + BF_HI(u2v.x)) + dv * a1) * 0.25f;
            float v2 = (x0v.z + rdv * (BF_LO(u1v.y) + BF_LO(u2v.y)) + dv * a2) * 0.25f;
            float v3 = (x0v.w + rdv * (BF_HI(u1v.y) + BF_HI(u2v.y)) + dv * a3) * 0.25f;

            float ss = v0 * v0 + v1 * v1 + v2 * v2 + v3 * v3;
            ss += __shfl_xor(ss, 1);
            ss += __shfl_xor(ss, 2);
            ss += __shfl_xor(ss, 4);
            ss += __shfl_xor(ss, 8);
            float scale = 1.0f / fmaxf(sqrtf(ss), 1e-12f);

            float4 r = { v0 * scale, v1 * scale, v2 * scale, v3 * scale };
            *(float4*)(outp + o) = r;
        }
    }
    if (blockIdx.x == 0 && threadIdx.x == 0)
        outp[(size_t)N_NODES * EMBED_DIM] = 0.0f;  // align_loss
}

#undef BF_LO
#undef BF_HI

// ---------------------------------------------------------------------------
extern "C" void kernel_launch(void* const* d_in, const int* in_sizes, int n_in,
                              void* d_out, int out_size, void* d_ws, size_t ws_size,
                              hipStream_t stream) {
    const float* user_w     = (const float*)d_in[0];
    const float* artist_w   = (const float*)d_in[1];
    const float* album_w    = (const float*)d_in[2];
    const float* audio      = (const float*)d_in[3];
    const float* edge_attr  = (const float*)d_in[4];
    const float* ew         = (const float*)d_in[5];
    const float* w1         = (const float*)d_in[6];
    const float* b1         = (const float*)d_in[7];
    const float* w2         = (const float*)d_in[8];
    const float* b2         = (const float*)d_in[9];
    const int*   edge_index = (const int*)d_in[10];
    const int*   artist_ids = (const int*)d_in[11];
    const int*   album_ids  = (const int*)d_in[12];
    float* out = (float*)d_out;

    float* ws = (float*)d_ws;
    // Persistent regions (float-unit offsets):
    unsigned short* y0 = (unsigned short*)ws;                // 9.6M bf16
    unsigned short* y1 = (unsigned short*)(ws + 4800000);    // 9.6M bf16
    unsigned short* y2 = (unsigned short*)(ws + 9600000);    // 9.6M bf16
    float* dinv    = ws + 14400000;                          // 150k floats
    float* dinv2   = ws + 14560000;                          // 150k floats
    float* rd      = ws + 14720000;                          // 150k floats
    int*  row_ptr  = (int*)(ws + 14880000);                  // 150001 ints
    int2* csr_pair = (int2*)(ws + 15040000);                 // padded-16 CSR
                                                             // (+64 tail)
    // Transients aliased into y0/y1 regions (dead before init_x/propagate):
    int*   cnt     = (int*)ws;                               // 150k ints
    int*   rank    = (int*)(ws + 150000);                    // 1.25M ints
    int*   part    = (int*)(ws + 1600000);                   // 147 ints
    int*   baseoff = (int*)(ws + 1601000);                   // 147 ints
    int2*  epair   = (int2*)(ws + 1700000);                  // 1.25M pairs
    int*   perm    = (int*)(ws + 4800000);                   // in y1 region

    const int B = 256;
    const int egrid   = (NUM_EDGES + B - 1) / B;             // 1 edge/thread
    const int egrid4  = (NUM_EDGES / 4 + B - 1) / B;         // 4 edges/thread
    const int ngrid   = (N_NODES * EMBED_DIM) / B;           // wave-per-node
    const int ngrid16 = (N_NODES * 16) / B;                  // 16-lane-per-node
    const int pgrid   = (N_NODES / NPW * 64) / B;            // NPW-nodes-per-wave

    hipMemsetAsync(cnt, 0, N_NODES * sizeof(int), stream);

    hist_mlp<<<egrid, B, 0, stream>>>(
        edge_attr, ew, w1, b1, w2, b2, edge_index, cnt, rank, epair);

    scan_partial<<<SCAN_NB, SCAN_B, 0, stream>>>(cnt, part);
    scan_offsets<<<1, 256, 0, stream>>>(part, baseoff);
    scan_apply<<<SCAN_NB, SCAN_B, 0, stream>>>(cnt, baseoff, row_ptr);

    scatter_perm<<<egrid4, B, 0, stream>>>(edge_index, rank, row_ptr, perm);

    pair_build<<<ngrid16, B, 0, stream>>>(
        row_ptr, cnt, perm, epair, csr_pair, dinv, dinv2, rd);

    init_x<<<ngrid, B, 0, stream>>>(
        user_w, artist_w, album_w, audio, artist_ids, album_ids,
        dinv, out, y0);

    propagate_mid<<<pgrid, B, 0, stream>>>(row_ptr, csr_pair, dinv2, y0, y1);
    propagate_mid<<<pgrid, B, 0, stream>>>(row_ptr, csr_pair, dinv2, y1, y2);
    propagate_final<<<pgrid, B, 0, stream>>>(row_ptr, csr_pair, dinv, rd, y1, y2, out);
}